// Round 10
// baseline (81.803 us; speedup 1.0000x reference)
//
#include <hip/hip_runtime.h>

#define LAM 0.5f
#define MU 0.1f
#define RHO 0.05f
#define CLS 10
#define ROWS 256
#define SG 16          // s-values per block
#define L2E  1.4426950408889634f
#define HL2E 0.7213475204444817f
#define EINV 0.36787944117144233f

typedef const __attribute__((address_space(1))) char gchar;
typedef __attribute__((address_space(3))) char lchar;

__device__ __forceinline__ float waveReduceSum(float v) {
#pragma unroll
    for (int m = 1; m < 64; m <<= 1) v += __shfl_xor(v, m, 64);
    return v;
}

// 3-level butterfly: lane l ends with the sum of its 8-lane group (l>>3).
__device__ __forceinline__ float waveReduce8(float v) {
    v += __shfl_xor(v, 1, 64);
    v += __shfl_xor(v, 2, 64);
    v += __shfl_xor(v, 4, 64);
    return v;
}

// Stage 2560 B (64 rows x 10 floats) per wave: global -> LDS direct DMA.
// Wave slices are PRIVATE (thread tid reads row tid from its own wave's slice),
// so no __syncthreads is needed anywhere in the kernel.
__device__ __forceinline__ void dmaTile(const float4* srcBase, float* dstBase,
                                        int wid, int lane) {
    const float4* s = srcBase + wid * 160;
    float* d = dstBase + wid * 640;
    __builtin_amdgcn_global_load_lds((gchar*)(const char*)(s + lane),
                                     (lchar*)(char*)d, 16, 0, 0);
    __builtin_amdgcn_global_load_lds((gchar*)(const char*)(s + 64 + lane),
                                     (lchar*)(char*)(d + 256), 16, 0, 0);
    if (lane < 32)
        __builtin_amdgcn_global_load_lds((gchar*)(const char*)(s + 128 + lane),
                                         (lchar*)(char*)(d + 512), 16, 0, 0);
}

// Main: depth-1 DMA pipeline, LDS exactly 20480 B -> 8 blocks/CU, grid 2048 =
// one exact round. Per-tile reduction cut to 3 butterfly levels (8-lane
// groups); group partials kept in 6 registers (lane 8g+(si&7) keeps group g's
// sum for tile si; A/B register pair selected by si>>3 at compile time via
// full unroll). Zero barriers, zero atomics.
__global__ __launch_bounds__(256) void main_kernel(
    const float* __restrict__ noise, const float* __restrict__ pred,
    const int* __restrict__ tgt,
    float* __restrict__ wstarPart, float* __restrict__ partials, int B) {
    __shared__ float buf0[ROWS * CLS];   // 10240 B
    __shared__ float buf1[ROWS * CLS];   // 10240 B  (total 20480 exactly)

    const int tid = threadIdx.x;
    const int lane = tid & 63, wid = tid >> 6;
    const int nChunks = B / ROWS;               // 256
    const int chunk = (int)blockIdx.x % nChunks;
    const int sg = (int)blockIdx.x / nChunks;   // 0..7
    const int rowBase = chunk * ROWS;
    const int s0 = sg * SG;
    const int nPart = nChunks * 32;             // 8192

    const int t = tgt[rowBase + tid];           // only non-DMA global load
    __builtin_amdgcn_sched_barrier(0);

    const size_t sStride4 = (size_t)B * CLS / 4;
    const float4* noiseT = (const float4*)(noise + (size_t)rowBase * CLS)
                           + (size_t)s0 * sStride4;

    dmaTile((const float4*)(pred + (size_t)rowBase * CLS), buf0, wid, lane);
    dmaTile(noiseT, buf1, wid, lane);
    asm volatile("s_waitcnt vmcnt(3)" ::: "memory");   // tgt + pred done
    __builtin_amdgcn_sched_barrier(0);

    // ---- logp from buf0 (wave-private) ----
    float x[CLS];
    {
        const float2* r2 = (const float2*)(buf0 + tid * CLS);
#pragma unroll
        for (int j = 0; j < 5; j++) { float2 v = r2[j]; x[2*j] = v.x; x[2*j+1] = v.y; }
    }
    float mx = x[0];
#pragma unroll
    for (int c = 1; c < CLS; c++) mx = fmaxf(mx, x[c]);
    float z = 0.f;
#pragma unroll
    for (int c = 0; c < CLS; c++) z += __expf(x[c] - mx);
    float lse = mx + __logf(z);

    float lp[CLS], lpk[CLS], kk[CLS], bias[CLS];
    float xt = 0.f;
#pragma unroll
    for (int c = 0; c < CLS; c++) {
        bool e = (c == t);
        float lpv = x[c] - lse;
        lp[c] = lpv;
        kk[c] = e ? EINV : 1.f;
        lpk[c] = lpv * kk[c];
        bias[c] = e ? L2E : 0.f;
        xt += e ? x[c] : 0.f;
    }
    float keepW;
    {
        float rce = waveReduceSum(lse - xt);   // once per kernel: full reduce
        keepW = (lane == 48) ? rce : 0.f;
    }

    // 6 keep registers: group partials for tiles 0-7 (A) and 8-15 (B).
    float keepA0 = 0.f, keepA1 = 0.f, keepA2 = 0.f;
    float keepB0 = 0.f, keepB1 = 0.f, keepB2 = 0.f;

    const float4* srcNext = noiseT + sStride4;

    // softmax(n+oh): pl = exp2(fma(n,HL2E,bias)) = exp(n/2+oh);
    // LAM-term uses pl; full term e = pl^2 * k (k = e^{-oh}).
#define BODY(CUR, NXT, SI)                                                     \
    {                                                                          \
        const int si = (SI);                                                   \
        if (si < SG - 1) {                                                     \
            dmaTile(srcNext, (NXT), wid, lane);                                \
            srcNext += sStride4;                                               \
            asm volatile("s_waitcnt vmcnt(3)" ::: "memory");                   \
        } else {                                                               \
            asm volatile("s_waitcnt vmcnt(0)" ::: "memory");                   \
        }                                                                      \
        __builtin_amdgcn_sched_barrier(0);                                     \
        float nn[CLS];                                                         \
        {                                                                      \
            const float2* r2 = (const float2*)((CUR) + tid * CLS);             \
            _Pragma("unroll")                                                  \
            for (int j = 0; j < 5; j++) {                                      \
                float2 v = r2[j]; nn[2*j] = v.x; nn[2*j+1] = v.y;              \
            }                                                                  \
        }                                                                      \
        float Z = 0.f, Zl = 0.f, dot = 0.f, dotl = 0.f, sq = 0.f;              \
        _Pragma("unroll")                                                      \
        for (int c = 0; c < CLS; c++) {                                        \
            float a  = fmaf(nn[c], HL2E, bias[c]);                             \
            float pl = exp2f(a);                                               \
            float t1 = pl * pl;                                                \
            Zl += pl;                                                          \
            dotl = fmaf(pl, lp[c], dotl);                                      \
            Z    = fmaf(t1, kk[c], Z);                                         \
            dot  = fmaf(t1, lpk[c], dot);                                      \
            sq   = fmaf(nn[c], nn[c], sq);                                     \
        }                                                                      \
        float rw  = waveReduce8(__fdividef(dot, Z));                           \
        float rwt = waveReduce8(__fdividef(dotl, Zl));                         \
        float rn2 = waveReduce8(sq);                                           \
        bool k8 = (lane & 7) == (si & 7);                                      \
        if (si < 8) {                                                          \
            keepA0 = k8 ? rw  : keepA0;                                        \
            keepA1 = k8 ? rwt : keepA1;                                        \
            keepA2 = k8 ? rn2 : keepA2;                                        \
        } else {                                                               \
            keepB0 = k8 ? rw  : keepB0;                                        \
            keepB1 = k8 ? rwt : keepB1;                                        \
            keepB2 = k8 ? rn2 : keepB2;                                        \
        }                                                                      \
    }

#pragma unroll
    for (int sb = 0; sb < SG; sb += 2) {
        BODY(buf1, buf0, sb);
        BODY(buf0, buf1, sb + 1);
    }
#undef BODY

    // ---- per-wave group partials -> global ----
    // Thread lane = 8g + j holds: tiles j (A regs) and j+8 (B regs), group g.
    {
        const int g = lane >> 3, j = lane & 7;
        const size_t col = (size_t)chunk * 32 + wid * 8 + g;
        const size_t rowA = (size_t)(s0 + j) * 3;
        const size_t rowB = (size_t)(s0 + j + 8) * 3;
        partials[(rowA + 0) * nPart + col] = keepA0;
        partials[(rowA + 1) * nPart + col] = keepA1;
        partials[(rowA + 2) * nPart + col] = keepA2;
        partials[(rowB + 0) * nPart + col] = keepB0;
        partials[(rowB + 1) * nPart + col] = keepB1;
        partials[(rowB + 2) * nPart + col] = keepB2;
    }
    if (sg == 0 && lane == 48)
        wstarPart[chunk * 4 + wid] = keepW;
}

// Per-s reduction over 8192 group-partials + hinge -> scPart[s].
// Each block also (redundantly) reduces wstarPart for its own wstar.
__global__ __launch_bounds__(256) void reduce_kernel(
    const float* __restrict__ partials, const float* __restrict__ wstarPart,
    float* __restrict__ scPart, float* __restrict__ wsum, int B, int nPart) {
    __shared__ float red[4][4];
    const int s = blockIdx.x, tid = threadIdx.x;
    const int lane = tid & 63, wid = tid >> 6;
    const float* p = partials + (size_t)s * 3 * nPart;
    float a = 0.f, b = 0.f, c = 0.f, wv = 0.f;
    for (int j = tid; j < nPart; j += 256) {
        a += p[j];
        b += p[nPart + j];
        c += p[2 * nPart + j];
    }
    for (int j = tid; j < 1024; j += 256) wv += wstarPart[j];
    a = waveReduceSum(a); b = waveReduceSum(b);
    c = waveReduceSum(c); wv = waveReduceSum(wv);
    if (lane == 0) { red[wid][0] = a; red[wid][1] = b; red[wid][2] = c; red[wid][3] = wv; }
    __syncthreads();
    if (tid == 0) {
        float ra = red[0][0] + red[1][0] + red[2][0] + red[3][0];
        float rb = red[0][1] + red[1][1] + red[2][1] + red[3][1];
        float rc = red[0][2] + red[1][2] + red[2][2] + red[3][2];
        float rw = red[0][3] + red[1][3] + red[2][3] + red[3][3];
        float invB = 1.0f / (float)B;
        float wstar = rw * invB;
        float w  = -ra * invB;
        float wt = -rb * invB;
        float n2 =  rc;
        float sc1 = fmaxf(wstar - wt, 0.f);
        float sc2 = fmaxf(wstar - w + MU * n2 * 0.5f, 0.f);
        float sc3 = fmaxf(wt - (1.f - LAM) * wstar + LAM * w
                          + MU * LAM * (1.f - LAM) * n2 * 0.5f, 0.f);
        scPart[s] = sc1 + sc2 + sc3;
        if (s == 0) wsum[0] = rw;
    }
}

// Finalize: out = wstar + RHO * sum(scPart).
__global__ __launch_bounds__(256) void finalize_kernel(
    const float* __restrict__ scPart, const float* __restrict__ wsum,
    float* __restrict__ out, int B, int S) {
    __shared__ float red[2];
    const int tid = threadIdx.x, lane = tid & 63, wid = tid >> 6;
    float v = (tid < S) ? scPart[tid] : 0.f;
    if (tid < 128) {
        float r = waveReduceSum(v);
        if (lane == 0) red[wid] = r;
    }
    __syncthreads();
    if (tid == 0)
        out[0] = wsum[0] / (float)B + RHO * (red[0] + red[1]);
}

extern "C" void kernel_launch(void* const* d_in, const int* in_sizes, int n_in,
                              void* d_out, int out_size, void* d_ws, size_t ws_size,
                              hipStream_t stream) {
    const float* pred  = (const float*)d_in[0];
    const int*   tgt   = (const int*)d_in[1];
    const float* noise = (const float*)d_in[2];
    float* out = (float*)d_out;

    int B = in_sizes[1];                 // 65536
    int S = in_sizes[2] / in_sizes[0];   // 128
    int nChunks = B / ROWS;              // 256
    int nSG = S / SG;                    // 8
    int nPart = nChunks * 32;            // 8192

    float* ws = (float*)d_ws;
    float* wstarPart = ws;               // [1024]
    float* scPart    = ws + 1024;        // [128]
    float* wsum      = ws + 1152;        // [1]
    float* partials  = ws + 2048;        // [384][8192]

    main_kernel<<<nSG * nChunks, 256, 0, stream>>>(noise, pred, tgt,
                                                   wstarPart, partials, B);
    reduce_kernel<<<S, 256, 0, stream>>>(partials, wstarPart, scPart, wsum,
                                         B, nPart);
    finalize_kernel<<<1, 256, 0, stream>>>(scPart, wsum, out, B, S);
}

// Round 11
// 75.074 us; speedup vs baseline: 1.0896x; 1.0896x over previous
//
#include <hip/hip_runtime.h>

#define LAM 0.5f
#define MU 0.1f
#define RHO 0.05f
#define CLS 10
#define ROWS 256
#define SG 16          // s-values per block
#define L2E  1.4426950408889634f
#define HL2E 0.7213475204444817f
#define EINV 0.36787944117144233f

typedef const __attribute__((address_space(1))) char gchar;
typedef __attribute__((address_space(3))) char lchar;

__device__ __forceinline__ float waveReduceSum(float v) {
#pragma unroll
    for (int m = 1; m < 64; m <<= 1) v += __shfl_xor(v, m, 64);
    return v;
}

// Wave sum on the VALU pipe only (no DS ops): 6x v_add_f32 with DPP row ops,
// total lands in lane 63, broadcast via readlane. rocPRIM-style chain.
__device__ __forceinline__ float waveSumDPP(float v) {
#define DPP_ADD(CTRL)                                                          \
    v += __int_as_float(__builtin_amdgcn_update_dpp(                           \
        0, __float_as_int(v), (CTRL), 0xf, 0xf, true));
    DPP_ADD(0x111)  // row_shr:1
    DPP_ADD(0x112)  // row_shr:2
    DPP_ADD(0x114)  // row_shr:4
    DPP_ADD(0x118)  // row_shr:8
    DPP_ADD(0x142)  // row_bcast:15
    DPP_ADD(0x143)  // row_bcast:31
#undef DPP_ADD
    return __int_as_float(__builtin_amdgcn_readlane(__float_as_int(v), 63));
}

// Stage 2560 B (64 rows x 10 floats) per wave: global -> LDS direct DMA.
// Wave slices are PRIVATE (thread tid reads row tid from its own wave's slice),
// so no __syncthreads is needed anywhere in the kernel.
__device__ __forceinline__ void dmaTile(const float4* srcBase, float* dstBase,
                                        int wid, int lane) {
    const float4* s = srcBase + wid * 160;
    float* d = dstBase + wid * 640;
    __builtin_amdgcn_global_load_lds((gchar*)(const char*)(s + lane),
                                     (lchar*)(char*)d, 16, 0, 0);
    __builtin_amdgcn_global_load_lds((gchar*)(const char*)(s + 64 + lane),
                                     (lchar*)(char*)(d + 256), 16, 0, 0);
    if (lane < 32)
        __builtin_amdgcn_global_load_lds((gchar*)(const char*)(s + 128 + lane),
                                         (lchar*)(char*)(d + 512), 16, 0, 0);
}

// Main: depth-1 DMA pipeline, LDS exactly 20480 B -> 8 blocks/CU, grid 2048 =
// one exact round. Per-tile cross-lane reduction runs entirely on the VALU
// pipe (DPP), keeping the DS pipe free for row reads + DMA writes. Per-wave
// (si,k) partials live in a per-lane "keep" register (lane 3*si+k holds value
// k of tile si; lane 48 holds the wstar partial). Zero barriers, zero atomics.
__global__ __launch_bounds__(256) void main_kernel(
    const float* __restrict__ noise, const float* __restrict__ pred,
    const int* __restrict__ tgt,
    float* __restrict__ wstarPart, float* __restrict__ partials, int B) {
    __shared__ float buf0[ROWS * CLS];   // 10240 B
    __shared__ float buf1[ROWS * CLS];   // 10240 B  (total 20480 exactly)

    const int tid = threadIdx.x;
    const int lane = tid & 63, wid = tid >> 6;
    const int nChunks = B / ROWS;               // 256
    const int chunk = (int)blockIdx.x % nChunks;
    const int sg = (int)blockIdx.x / nChunks;   // 0..7
    const int rowBase = chunk * ROWS;
    const int s0 = sg * SG;
    const int nPart = nChunks * 4;              // 1024

    const int t = tgt[rowBase + tid];           // only non-DMA global load
    __builtin_amdgcn_sched_barrier(0);

    const size_t sStride4 = (size_t)B * CLS / 4;
    const float4* noiseT = (const float4*)(noise + (size_t)rowBase * CLS)
                           + (size_t)s0 * sStride4;

    dmaTile((const float4*)(pred + (size_t)rowBase * CLS), buf0, wid, lane);
    dmaTile(noiseT, buf1, wid, lane);
    asm volatile("s_waitcnt vmcnt(3)" ::: "memory");   // tgt + pred done
    __builtin_amdgcn_sched_barrier(0);

    // ---- logp from buf0 (wave-private) ----
    float x[CLS];
    {
        const float2* r2 = (const float2*)(buf0 + tid * CLS);
#pragma unroll
        for (int j = 0; j < 5; j++) { float2 v = r2[j]; x[2*j] = v.x; x[2*j+1] = v.y; }
    }
    float mx = x[0];
#pragma unroll
    for (int c = 1; c < CLS; c++) mx = fmaxf(mx, x[c]);
    float z = 0.f;
#pragma unroll
    for (int c = 0; c < CLS; c++) z += __expf(x[c] - mx);
    float lse = mx + __logf(z);

    float lp[CLS], lpk[CLS], kk[CLS], bias[CLS];
    float xt = 0.f;
#pragma unroll
    for (int c = 0; c < CLS; c++) {
        bool e = (c == t);
        float lpv = x[c] - lse;
        lp[c] = lpv;
        kk[c] = e ? EINV : 1.f;
        lpk[c] = lpv * kk[c];
        bias[c] = e ? L2E : 0.f;
        xt += e ? x[c] : 0.f;
    }
    float keep;
    {
        float rce = waveSumDPP(lse - xt);
        keep = (lane == 48) ? rce : 0.f;
    }

    const float4* srcNext = noiseT + sStride4;

    // softmax(n+oh): pl = exp2(fma(n,HL2E,bias)) = exp(n/2+oh);
    // LAM-term uses pl; full term e = pl^2 * k (k = e^{-oh}).
#define BODY(CUR, NXT, SI)                                                     \
    {                                                                          \
        const int si = (SI);                                                   \
        if (si < SG - 1) {                                                     \
            dmaTile(srcNext, (NXT), wid, lane);                                \
            srcNext += sStride4;                                               \
            asm volatile("s_waitcnt vmcnt(3)" ::: "memory");                   \
        } else {                                                               \
            asm volatile("s_waitcnt vmcnt(0)" ::: "memory");                   \
        }                                                                      \
        __builtin_amdgcn_sched_barrier(0);                                     \
        float nn[CLS];                                                         \
        {                                                                      \
            const float2* r2 = (const float2*)((CUR) + tid * CLS);             \
            _Pragma("unroll")                                                  \
            for (int j = 0; j < 5; j++) {                                      \
                float2 v = r2[j]; nn[2*j] = v.x; nn[2*j+1] = v.y;              \
            }                                                                  \
        }                                                                      \
        float Z = 0.f, Zl = 0.f, dot = 0.f, dotl = 0.f, sq = 0.f;              \
        _Pragma("unroll")                                                      \
        for (int c = 0; c < CLS; c++) {                                        \
            float a  = fmaf(nn[c], HL2E, bias[c]);                             \
            float pl = exp2f(a);                                               \
            float t1 = pl * pl;                                                \
            Zl += pl;                                                          \
            dotl = fmaf(pl, lp[c], dotl);                                      \
            Z    = fmaf(t1, kk[c], Z);                                         \
            dot  = fmaf(t1, lpk[c], dot);                                      \
            sq   = fmaf(nn[c], nn[c], sq);                                     \
        }                                                                      \
        float rw  = waveSumDPP(__fdividef(dot, Z));                            \
        float rwt = waveSumDPP(__fdividef(dotl, Zl));                          \
        float rn2 = waveSumDPP(sq);                                            \
        keep = (lane == si * 3    ) ? rw  : keep;                              \
        keep = (lane == si * 3 + 1) ? rwt : keep;                              \
        keep = (lane == si * 3 + 2) ? rn2 : keep;                              \
    }

    for (int sb = 0; sb < SG; sb += 2) {
        BODY(buf1, buf0, sb);
        BODY(buf0, buf1, sb + 1);
    }
#undef BODY

    // ---- per-wave partials -> global: lane 3*si+k holds (si,k) value ----
    if (lane < SG * 3) {
        int si = lane / 3, k = lane - 3 * si;
        partials[(size_t)((s0 + si) * 3 + k) * nPart + chunk * 4 + wid] = keep;
    }
    if (sg == 0 && lane == 48)
        wstarPart[chunk * 4 + wid] = keep;
}

// Per-s reduction over 1024 wave-partials + hinge -> scPart[s].
// Only block 0 reduces wstarPart (wstar itself comes via wsum in finalize;
// here every block needs wstar for the hinge, so all blocks still reduce it —
// it is only 1024 L2-resident floats; keep for correctness of hinge).
__global__ __launch_bounds__(256) void reduce_kernel(
    const float* __restrict__ partials, const float* __restrict__ wstarPart,
    float* __restrict__ scPart, float* __restrict__ wsum, int B, int nPart) {
    __shared__ float red[4][4];
    const int s = blockIdx.x, tid = threadIdx.x;
    const int lane = tid & 63, wid = tid >> 6;
    const float* p = partials + (size_t)s * 3 * nPart;
    float a = 0.f, b = 0.f, c = 0.f, wv = 0.f;
    for (int j = tid; j < nPart; j += 256) {
        a  += p[j];
        b  += p[nPart + j];
        c  += p[2 * nPart + j];
        wv += wstarPart[j];
    }
    a = waveReduceSum(a); b = waveReduceSum(b);
    c = waveReduceSum(c); wv = waveReduceSum(wv);
    if (lane == 0) { red[wid][0] = a; red[wid][1] = b; red[wid][2] = c; red[wid][3] = wv; }
    __syncthreads();
    if (tid == 0) {
        float ra = red[0][0] + red[1][0] + red[2][0] + red[3][0];
        float rb = red[0][1] + red[1][1] + red[2][1] + red[3][1];
        float rc = red[0][2] + red[1][2] + red[2][2] + red[3][2];
        float rw = red[0][3] + red[1][3] + red[2][3] + red[3][3];
        float invB = 1.0f / (float)B;
        float wstar = rw * invB;
        float w  = -ra * invB;
        float wt = -rb * invB;
        float n2 =  rc;
        float sc1 = fmaxf(wstar - wt, 0.f);
        float sc2 = fmaxf(wstar - w + MU * n2 * 0.5f, 0.f);
        float sc3 = fmaxf(wt - (1.f - LAM) * wstar + LAM * w
                          + MU * LAM * (1.f - LAM) * n2 * 0.5f, 0.f);
        scPart[s] = sc1 + sc2 + sc3;
        if (s == 0) wsum[0] = rw;
    }
}

// Finalize: out = wstar + RHO * sum(scPart).
__global__ __launch_bounds__(256) void finalize_kernel(
    const float* __restrict__ scPart, const float* __restrict__ wsum,
    float* __restrict__ out, int B, int S) {
    __shared__ float red[2];
    const int tid = threadIdx.x, lane = tid & 63, wid = tid >> 6;
    float v = (tid < S) ? scPart[tid] : 0.f;
    if (tid < 128) {
        float r = waveReduceSum(v);
        if (lane == 0) red[wid] = r;
    }
    __syncthreads();
    if (tid == 0)
        out[0] = wsum[0] / (float)B + RHO * (red[0] + red[1]);
}

extern "C" void kernel_launch(void* const* d_in, const int* in_sizes, int n_in,
                              void* d_out, int out_size, void* d_ws, size_t ws_size,
                              hipStream_t stream) {
    const float* pred  = (const float*)d_in[0];
    const int*   tgt   = (const int*)d_in[1];
    const float* noise = (const float*)d_in[2];
    float* out = (float*)d_out;

    int B = in_sizes[1];                 // 65536
    int S = in_sizes[2] / in_sizes[0];   // 128
    int nChunks = B / ROWS;              // 256
    int nSG = S / SG;                    // 8
    int nPart = nChunks * 4;             // 1024

    float* ws = (float*)d_ws;
    float* wstarPart = ws;               // [1024]
    float* scPart    = ws + 1024;        // [128]
    float* wsum      = ws + 1152;        // [1]
    float* partials  = ws + 2048;        // [384][1024]

    main_kernel<<<nSG * nChunks, 256, 0, stream>>>(noise, pred, tgt,
                                                   wstarPart, partials, B);
    reduce_kernel<<<S, 256, 0, stream>>>(partials, wstarPart, scPart, wsum,
                                         B, nPart);
    finalize_kernel<<<1, 256, 0, stream>>>(scPart, wsum, out, B, S);
}

// Round 12
// 73.796 us; speedup vs baseline: 1.1085x; 1.0173x over previous
//
#include <hip/hip_runtime.h>

#define LAM 0.5f
#define MU 0.1f
#define RHO 0.05f
#define CLS 10
#define ROWS 256
#define SG 32          // s-values per block
#define L2E  1.4426950408889634f
#define HL2E 0.7213475204444817f
#define EINV 0.36787944117144233f

typedef const __attribute__((address_space(1))) char gchar;
typedef __attribute__((address_space(3))) char lchar;

__device__ __forceinline__ float waveReduceSum(float v) {
#pragma unroll
    for (int m = 1; m < 64; m <<= 1) v += __shfl_xor(v, m, 64);
    return v;
}

// Wave sum on the VALU pipe only (no DS ops): 6x v_add_f32 with DPP row ops,
// total lands in lane 63, broadcast via readlane.
__device__ __forceinline__ float waveSumDPP(float v) {
#define DPP_ADD(CTRL)                                                          \
    v += __int_as_float(__builtin_amdgcn_update_dpp(                           \
        0, __float_as_int(v), (CTRL), 0xf, 0xf, true));
    DPP_ADD(0x111)  // row_shr:1
    DPP_ADD(0x112)  // row_shr:2
    DPP_ADD(0x114)  // row_shr:4
    DPP_ADD(0x118)  // row_shr:8
    DPP_ADD(0x142)  // row_bcast:15
    DPP_ADD(0x143)  // row_bcast:31
#undef DPP_ADD
    return __int_as_float(__builtin_amdgcn_readlane(__float_as_int(v), 63));
}

// Stage 2560 B (64 rows x 10 floats) per wave: global -> LDS direct DMA.
// Wave slices are PRIVATE (thread tid reads row tid from its own wave's slice),
// so no __syncthreads is needed anywhere in the kernel.
__device__ __forceinline__ void dmaTile(const float4* srcBase, float* dstBase,
                                        int wid, int lane) {
    const float4* s = srcBase + wid * 160;
    float* d = dstBase + wid * 640;
    __builtin_amdgcn_global_load_lds((gchar*)(const char*)(s + lane),
                                     (lchar*)(char*)d, 16, 0, 0);
    __builtin_amdgcn_global_load_lds((gchar*)(const char*)(s + 64 + lane),
                                     (lchar*)(char*)(d + 256), 16, 0, 0);
    if (lane < 32)
        __builtin_amdgcn_global_load_lds((gchar*)(const char*)(s + 128 + lane),
                                         (lchar*)(char*)(d + 512), 16, 0, 0);
}

// Main: SG=32 s-values/block, 3-buffer LDS ring (30720 B), DEPTH-2 DMA
// prefetch (vmcnt(6) steady state). Grid 1024 = 4 blocks/CU exact,
// 16 waves/CU, 82 KB outstanding DMA per CU. Per-wave (si,k) partials in two
// keep registers (lanes 0..47; tiles 0-15 -> keepX, 16-31 -> keepY); lane 48
// holds the wstar partial. Zero barriers, zero atomics. Fully unrolled so all
// %3 buffer indices and lane constants fold at compile time.
__global__ __launch_bounds__(256) void main_kernel(
    const float* __restrict__ noise, const float* __restrict__ pred,
    const int* __restrict__ tgt,
    float* __restrict__ wstarPart, float* __restrict__ partials, int B) {
    __shared__ float bufb[3 * ROWS * CLS / 1 * 1];   // 3 x 10240 B = 30720 B
    const int tid = threadIdx.x;
    const int lane = tid & 63, wid = tid >> 6;
    const int nChunks = B / ROWS;               // 256
    const int chunk = (int)blockIdx.x % nChunks;
    const int sg = (int)blockIdx.x / nChunks;   // 0..3
    const int rowBase = chunk * ROWS;
    const int s0 = sg * SG;
    const int nPart = nChunks * 4;              // 1024

    const int t = tgt[rowBase + tid];           // only non-DMA global load
    __builtin_amdgcn_sched_barrier(0);

    const size_t sStride4 = (size_t)B * CLS / 4;
    const float4* noiseT = (const float4*)(noise + (size_t)rowBase * CLS)
                           + (size_t)s0 * sStride4;

    // prologue: pred -> buf2; tiles 0,1 -> buf0,buf1   (tgt+10 outstanding)
    dmaTile((const float4*)(pred + (size_t)rowBase * CLS), bufb + 2 * 2560, wid, lane);
    dmaTile(noiseT,            bufb,        wid, lane);
    dmaTile(noiseT + sStride4, bufb + 2560, wid, lane);
    asm volatile("s_waitcnt vmcnt(6)" ::: "memory");   // tgt + pred done
    __builtin_amdgcn_sched_barrier(0);

    // ---- logp from buf2 (wave-private) ----
    float x[CLS];
    {
        const float2* r2 = (const float2*)(bufb + 2 * 2560 + tid * CLS);
#pragma unroll
        for (int j = 0; j < 5; j++) { float2 v = r2[j]; x[2*j] = v.x; x[2*j+1] = v.y; }
    }
    float mx = x[0];
#pragma unroll
    for (int c = 1; c < CLS; c++) mx = fmaxf(mx, x[c]);
    float z = 0.f;
#pragma unroll
    for (int c = 0; c < CLS; c++) z += __expf(x[c] - mx);
    float lse = mx + __logf(z);

    float lp[CLS], lpk[CLS], kk[CLS], bias[CLS];
    float xt = 0.f;
#pragma unroll
    for (int c = 0; c < CLS; c++) {
        bool e = (c == t);
        float lpv = x[c] - lse;
        lp[c] = lpv;
        kk[c] = e ? EINV : 1.f;
        lpk[c] = lpv * kk[c];
        bias[c] = e ? L2E : 0.f;
        xt += e ? x[c] : 0.f;
    }
    float keepW;
    {
        float rce = waveSumDPP(lse - xt);
        keepW = (lane == 48) ? rce : 0.f;
    }

    float keepX = 0.f, keepY = 0.f;   // (si,k) partials: tiles 0-15 / 16-31
    const float4* srcNext = noiseT + 2 * sStride4;

    // softmax(n+oh): pl = exp2(fma(n,HL2E,bias)) = exp(n/2+oh);
    // LAM-term uses pl; full term e = pl^2 * k (k = e^{-oh}).
#pragma unroll
    for (int it = 0; it < SG; ++it) {
        const float* CUR = bufb + (it % 3) * 2560;
        if (it < SG - 2) {
            dmaTile(srcNext, bufb + ((it + 2) % 3) * 2560, wid, lane);
            srcNext += sStride4;
            asm volatile("s_waitcnt vmcnt(6)" ::: "memory");   // tile `it` here
        } else if (it == SG - 2) {
            asm volatile("s_waitcnt vmcnt(3)" ::: "memory");
        } else {
            asm volatile("s_waitcnt vmcnt(0)" ::: "memory");
        }
        __builtin_amdgcn_sched_barrier(0);

        float nn[CLS];
        {
            const float2* r2 = (const float2*)(CUR + tid * CLS);
#pragma unroll
            for (int j = 0; j < 5; j++) { float2 v = r2[j]; nn[2*j] = v.x; nn[2*j+1] = v.y; }
        }
        float Z = 0.f, Zl = 0.f, dot = 0.f, dotl = 0.f, sq = 0.f;
#pragma unroll
        for (int c = 0; c < CLS; c++) {
            float a  = fmaf(nn[c], HL2E, bias[c]);
            float pl = exp2f(a);
            float t1 = pl * pl;
            Zl += pl;
            dotl = fmaf(pl, lp[c], dotl);
            Z    = fmaf(t1, kk[c], Z);
            dot  = fmaf(t1, lpk[c], dot);
            sq   = fmaf(nn[c], nn[c], sq);
        }
        float rw  = waveSumDPP(__fdividef(dot, Z));
        float rwt = waveSumDPP(__fdividef(dotl, Zl));
        float rn2 = waveSumDPP(sq);
        if (it < 16) {
            keepX = (lane == it * 3    ) ? rw  : keepX;
            keepX = (lane == it * 3 + 1) ? rwt : keepX;
            keepX = (lane == it * 3 + 2) ? rn2 : keepX;
        } else {
            const int j = it - 16;
            keepY = (lane == j * 3    ) ? rw  : keepY;
            keepY = (lane == j * 3 + 1) ? rwt : keepY;
            keepY = (lane == j * 3 + 2) ? rn2 : keepY;
        }
    }

    // ---- per-wave partials -> global: lane 3*si+k holds (si,k) ----
    if (lane < 48) {
        int si = lane / 3, k = lane - 3 * si;
        size_t col = (size_t)chunk * 4 + wid;
        partials[(size_t)((s0 + si) * 3 + k) * nPart + col] = keepX;
        partials[(size_t)((s0 + 16 + si) * 3 + k) * nPart + col] = keepY;
    }
    if (sg == 0 && lane == 48)
        wstarPart[chunk * 4 + wid] = keepW;
}

// Per-s reduction over 1024 wave-partials + hinge -> scPart[s].
__global__ __launch_bounds__(256) void reduce_kernel(
    const float* __restrict__ partials, const float* __restrict__ wstarPart,
    float* __restrict__ scPart, float* __restrict__ wsum, int B, int nPart) {
    __shared__ float red[4][4];
    const int s = blockIdx.x, tid = threadIdx.x;
    const int lane = tid & 63, wid = tid >> 6;
    const float* p = partials + (size_t)s * 3 * nPart;
    float a = 0.f, b = 0.f, c = 0.f, wv = 0.f;
    for (int j = tid; j < nPart; j += 256) {
        a  += p[j];
        b  += p[nPart + j];
        c  += p[2 * nPart + j];
        wv += wstarPart[j];
    }
    a = waveReduceSum(a); b = waveReduceSum(b);
    c = waveReduceSum(c); wv = waveReduceSum(wv);
    if (lane == 0) { red[wid][0] = a; red[wid][1] = b; red[wid][2] = c; red[wid][3] = wv; }
    __syncthreads();
    if (tid == 0) {
        float ra = red[0][0] + red[1][0] + red[2][0] + red[3][0];
        float rb = red[0][1] + red[1][1] + red[2][1] + red[3][1];
        float rc = red[0][2] + red[1][2] + red[2][2] + red[3][2];
        float rw = red[0][3] + red[1][3] + red[2][3] + red[3][3];
        float invB = 1.0f / (float)B;
        float wstar = rw * invB;
        float w  = -ra * invB;
        float wt = -rb * invB;
        float n2 =  rc;
        float sc1 = fmaxf(wstar - wt, 0.f);
        float sc2 = fmaxf(wstar - w + MU * n2 * 0.5f, 0.f);
        float sc3 = fmaxf(wt - (1.f - LAM) * wstar + LAM * w
                          + MU * LAM * (1.f - LAM) * n2 * 0.5f, 0.f);
        scPart[s] = sc1 + sc2 + sc3;
        if (s == 0) wsum[0] = rw;
    }
}

// Finalize: out = wstar + RHO * sum(scPart).
__global__ __launch_bounds__(256) void finalize_kernel(
    const float* __restrict__ scPart, const float* __restrict__ wsum,
    float* __restrict__ out, int B, int S) {
    __shared__ float red[2];
    const int tid = threadIdx.x, lane = tid & 63, wid = tid >> 6;
    float v = (tid < S) ? scPart[tid] : 0.f;
    if (tid < 128) {
        float r = waveReduceSum(v);
        if (lane == 0) red[wid] = r;
    }
    __syncthreads();
    if (tid == 0)
        out[0] = wsum[0] / (float)B + RHO * (red[0] + red[1]);
}

extern "C" void kernel_launch(void* const* d_in, const int* in_sizes, int n_in,
                              void* d_out, int out_size, void* d_ws, size_t ws_size,
                              hipStream_t stream) {
    const float* pred  = (const float*)d_in[0];
    const int*   tgt   = (const int*)d_in[1];
    const float* noise = (const float*)d_in[2];
    float* out = (float*)d_out;

    int B = in_sizes[1];                 // 65536
    int S = in_sizes[2] / in_sizes[0];   // 128
    int nChunks = B / ROWS;              // 256
    int nSG = S / SG;                    // 4
    int nPart = nChunks * 4;             // 1024

    float* ws = (float*)d_ws;
    float* wstarPart = ws;               // [1024]
    float* scPart    = ws + 1024;        // [128]
    float* wsum      = ws + 1152;        // [1]
    float* partials  = ws + 2048;        // [384][1024]

    main_kernel<<<nSG * nChunks, 256, 0, stream>>>(noise, pred, tgt,
                                                   wstarPart, partials, B);
    reduce_kernel<<<S, 256, 0, stream>>>(partials, wstarPart, scPart, wsum,
                                         B, nPart);
    finalize_kernel<<<1, 256, 0, stream>>>(scPart, wsum, out, B, S);
}

// Round 13
// 72.874 us; speedup vs baseline: 1.1225x; 1.0127x over previous
//
#include <hip/hip_runtime.h>

#define LAM 0.5f
#define MU 0.1f
#define RHO 0.05f
#define CLS 10
#define ROWS 256
#define SG 32          // s-values per block
#define L2E  1.4426950408889634f
#define HL2E 0.7213475204444817f
#define EINV 0.36787944117144233f

typedef const __attribute__((address_space(1))) char gchar;
typedef __attribute__((address_space(3))) char lchar;

__device__ __forceinline__ float waveReduceSum(float v) {
#pragma unroll
    for (int m = 1; m < 64; m <<= 1) v += __shfl_xor(v, m, 64);
    return v;
}

// Wave sum on the VALU pipe only (no DS ops): 6x v_add_f32 with DPP row ops,
// total lands in lane 63, broadcast via readlane.
__device__ __forceinline__ float waveSumDPP(float v) {
#define DPP_ADD(CTRL)                                                          \
    v += __int_as_float(__builtin_amdgcn_update_dpp(                           \
        0, __float_as_int(v), (CTRL), 0xf, 0xf, true));
    DPP_ADD(0x111)  // row_shr:1
    DPP_ADD(0x112)  // row_shr:2
    DPP_ADD(0x114)  // row_shr:4
    DPP_ADD(0x118)  // row_shr:8
    DPP_ADD(0x142)  // row_bcast:15
    DPP_ADD(0x143)  // row_bcast:31
#undef DPP_ADD
    return __int_as_float(__builtin_amdgcn_readlane(__float_as_int(v), 63));
}

// Stage 2560 B (64 rows x 10 floats) per wave: global -> LDS direct DMA.
// Wave slices are PRIVATE (thread tid reads row tid from its own wave's slice),
// so no __syncthreads is needed in the streaming loop.
__device__ __forceinline__ void dmaTile(const float4* srcBase, float* dstBase,
                                        int wid, int lane) {
    const float4* s = srcBase + wid * 160;
    float* d = dstBase + wid * 640;
    __builtin_amdgcn_global_load_lds((gchar*)(const char*)(s + lane),
                                     (lchar*)(char*)d, 16, 0, 0);
    __builtin_amdgcn_global_load_lds((gchar*)(const char*)(s + 64 + lane),
                                     (lchar*)(char*)(d + 256), 16, 0, 0);
    if (lane < 32)
        __builtin_amdgcn_global_load_lds((gchar*)(const char*)(s + 128 + lane),
                                         (lchar*)(char*)(d + 512), 16, 0, 0);
}

// Main: SG=32, 3-buffer LDS ring, depth-2 DMA prefetch (r12 structure,
// 73.8us) + end-of-kernel cross-wave pre-reduce so partials shrinks 4x to
// [384][256] (block-level, not wave-level). One __syncthreads total.
__global__ __launch_bounds__(256) void main_kernel(
    const float* __restrict__ noise, const float* __restrict__ pred,
    const int* __restrict__ tgt,
    float* __restrict__ wstarPart, float* __restrict__ partials, int B) {
    __shared__ float bufb[3 * ROWS * CLS];   // 30720 B
    __shared__ float partX[4][48];           // 768 B
    __shared__ float partY[4][48];           // 768 B
    __shared__ float wred[4];
    const int tid = threadIdx.x;
    const int lane = tid & 63, wid = tid >> 6;
    const int nChunks = B / ROWS;               // 256
    const int chunk = (int)blockIdx.x % nChunks;
    const int sg = (int)blockIdx.x / nChunks;   // 0..3
    const int rowBase = chunk * ROWS;
    const int s0 = sg * SG;

    const int t = tgt[rowBase + tid];           // only non-DMA global load
    __builtin_amdgcn_sched_barrier(0);

    const size_t sStride4 = (size_t)B * CLS / 4;
    const float4* noiseT = (const float4*)(noise + (size_t)rowBase * CLS)
                           + (size_t)s0 * sStride4;

    // prologue: pred -> buf2; tiles 0,1 -> buf0,buf1
    dmaTile((const float4*)(pred + (size_t)rowBase * CLS), bufb + 2 * 2560, wid, lane);
    dmaTile(noiseT,            bufb,        wid, lane);
    dmaTile(noiseT + sStride4, bufb + 2560, wid, lane);
    asm volatile("s_waitcnt vmcnt(6)" ::: "memory");   // tgt + pred done
    __builtin_amdgcn_sched_barrier(0);

    // ---- logp from buf2 (wave-private) ----
    float x[CLS];
    {
        const float2* r2 = (const float2*)(bufb + 2 * 2560 + tid * CLS);
#pragma unroll
        for (int j = 0; j < 5; j++) { float2 v = r2[j]; x[2*j] = v.x; x[2*j+1] = v.y; }
    }
    float mx = x[0];
#pragma unroll
    for (int c = 1; c < CLS; c++) mx = fmaxf(mx, x[c]);
    float z = 0.f;
#pragma unroll
    for (int c = 0; c < CLS; c++) z += __expf(x[c] - mx);
    float lse = mx + __logf(z);

    float lp[CLS], lpk[CLS], kk[CLS], bias[CLS];
    float xt = 0.f;
#pragma unroll
    for (int c = 0; c < CLS; c++) {
        bool e = (c == t);
        float lpv = x[c] - lse;
        lp[c] = lpv;
        kk[c] = e ? EINV : 1.f;
        lpk[c] = lpv * kk[c];
        bias[c] = e ? L2E : 0.f;
        xt += e ? x[c] : 0.f;
    }
    {
        float rce = waveSumDPP(lse - xt);
        if (lane == 0) wred[wid] = rce;
    }

    float keepX = 0.f, keepY = 0.f;   // (si,k) partials: tiles 0-15 / 16-31
    const float4* srcNext = noiseT + 2 * sStride4;

    // softmax(n+oh): pl = exp2(fma(n,HL2E,bias)) = exp(n/2+oh);
    // LAM-term uses pl; full term e = pl^2 * k (k = e^{-oh}).
#pragma unroll
    for (int it = 0; it < SG; ++it) {
        const float* CUR = bufb + (it % 3) * 2560;
        if (it < SG - 2) {
            dmaTile(srcNext, bufb + ((it + 2) % 3) * 2560, wid, lane);
            srcNext += sStride4;
            asm volatile("s_waitcnt vmcnt(6)" ::: "memory");   // tile `it` here
        } else if (it == SG - 2) {
            asm volatile("s_waitcnt vmcnt(3)" ::: "memory");
        } else {
            asm volatile("s_waitcnt vmcnt(0)" ::: "memory");
        }
        __builtin_amdgcn_sched_barrier(0);

        float nn[CLS];
        {
            const float2* r2 = (const float2*)(CUR + tid * CLS);
#pragma unroll
            for (int j = 0; j < 5; j++) { float2 v = r2[j]; nn[2*j] = v.x; nn[2*j+1] = v.y; }
        }
        float Z = 0.f, Zl = 0.f, dot = 0.f, dotl = 0.f, sq = 0.f;
#pragma unroll
        for (int c = 0; c < CLS; c++) {
            float a  = fmaf(nn[c], HL2E, bias[c]);
            float pl = exp2f(a);
            float t1 = pl * pl;
            Zl += pl;
            dotl = fmaf(pl, lp[c], dotl);
            Z    = fmaf(t1, kk[c], Z);
            dot  = fmaf(t1, lpk[c], dot);
            sq   = fmaf(nn[c], nn[c], sq);
        }
        float rw  = waveSumDPP(__fdividef(dot, Z));
        float rwt = waveSumDPP(__fdividef(dotl, Zl));
        float rn2 = waveSumDPP(sq);
        if (it < 16) {
            keepX = (lane == it * 3    ) ? rw  : keepX;
            keepX = (lane == it * 3 + 1) ? rwt : keepX;
            keepX = (lane == it * 3 + 2) ? rn2 : keepX;
        } else {
            const int j = it - 16;
            keepY = (lane == j * 3    ) ? rw  : keepY;
            keepY = (lane == j * 3 + 1) ? rwt : keepY;
            keepY = (lane == j * 3 + 2) ? rn2 : keepY;
        }
    }

    // ---- cross-wave pre-reduce (one barrier), then block-level store ----
    if (lane < 48) { partX[wid][lane] = keepX; partY[wid][lane] = keepY; }
    __syncthreads();
    if (tid < 48) {
        // lane tid = si*3+k  ->  row s0*3 + tid (X) / s0*3 + 48 + tid (Y)
        float vX = partX[0][tid] + partX[1][tid] + partX[2][tid] + partX[3][tid];
        float vY = partY[0][tid] + partY[1][tid] + partY[2][tid] + partY[3][tid];
        partials[(size_t)(s0 * 3 + tid) * nChunks + chunk] = vX;
        partials[(size_t)(s0 * 3 + 48 + tid) * nChunks + chunk] = vY;
    }
    if (sg == 0 && tid == 192)   // wave 3, lane 0: wred ready after barrier
        wstarPart[chunk] = wred[0] + wred[1] + wred[2] + wred[3];
}

// Per-s reduction over 256 block-partials + hinge -> scPart[s]. 4 KB/block.
__global__ __launch_bounds__(256) void reduce_kernel(
    const float* __restrict__ partials, const float* __restrict__ wstarPart,
    float* __restrict__ scPart, float* __restrict__ wsum, int B, int nPart) {
    __shared__ float red[4][4];
    const int s = blockIdx.x, tid = threadIdx.x;
    const int lane = tid & 63, wid = tid >> 6;
    const float* p = partials + (size_t)s * 3 * nPart;
    float a = p[tid], b = p[nPart + tid], c = p[2 * nPart + tid];
    float wv = wstarPart[tid];
    a = waveReduceSum(a); b = waveReduceSum(b);
    c = waveReduceSum(c); wv = waveReduceSum(wv);
    if (lane == 0) { red[wid][0] = a; red[wid][1] = b; red[wid][2] = c; red[wid][3] = wv; }
    __syncthreads();
    if (tid == 0) {
        float ra = red[0][0] + red[1][0] + red[2][0] + red[3][0];
        float rb = red[0][1] + red[1][1] + red[2][1] + red[3][1];
        float rc = red[0][2] + red[1][2] + red[2][2] + red[3][2];
        float rw = red[0][3] + red[1][3] + red[2][3] + red[3][3];
        float invB = 1.0f / (float)B;
        float wstar = rw * invB;
        float w  = -ra * invB;
        float wt = -rb * invB;
        float n2 =  rc;
        float sc1 = fmaxf(wstar - wt, 0.f);
        float sc2 = fmaxf(wstar - w + MU * n2 * 0.5f, 0.f);
        float sc3 = fmaxf(wt - (1.f - LAM) * wstar + LAM * w
                          + MU * LAM * (1.f - LAM) * n2 * 0.5f, 0.f);
        scPart[s] = sc1 + sc2 + sc3;
        if (s == 0) wsum[0] = rw;
    }
}

// Finalize: out = wstar + RHO * sum(scPart).
__global__ __launch_bounds__(256) void finalize_kernel(
    const float* __restrict__ scPart, const float* __restrict__ wsum,
    float* __restrict__ out, int B, int S) {
    __shared__ float red[2];
    const int tid = threadIdx.x, lane = tid & 63, wid = tid >> 6;
    float v = (tid < S) ? scPart[tid] : 0.f;
    if (tid < 128) {
        float r = waveReduceSum(v);
        if (lane == 0) red[wid] = r;
    }
    __syncthreads();
    if (tid == 0)
        out[0] = wsum[0] / (float)B + RHO * (red[0] + red[1]);
}

extern "C" void kernel_launch(void* const* d_in, const int* in_sizes, int n_in,
                              void* d_out, int out_size, void* d_ws, size_t ws_size,
                              hipStream_t stream) {
    const float* pred  = (const float*)d_in[0];
    const int*   tgt   = (const int*)d_in[1];
    const float* noise = (const float*)d_in[2];
    float* out = (float*)d_out;

    int B = in_sizes[1];                 // 65536
    int S = in_sizes[2] / in_sizes[0];   // 128
    int nChunks = B / ROWS;              // 256
    int nSG = S / SG;                    // 4

    float* ws = (float*)d_ws;
    float* wstarPart = ws;               // [256]
    float* scPart    = ws + 1024;        // [128]
    float* wsum      = ws + 1152;        // [1]
    float* partials  = ws + 2048;        // [384][256]

    main_kernel<<<nSG * nChunks, 256, 0, stream>>>(noise, pred, tgt,
                                                   wstarPart, partials, B);
    reduce_kernel<<<S, 256, 0, stream>>>(partials, wstarPart, scPart, wsum,
                                         B, nChunks);
    finalize_kernel<<<1, 256, 0, stream>>>(scPart, wsum, out, B, S);
}